// Round 11
// baseline (222.191 us; speedup 1.0000x reference)
//
#include <hip/hip_runtime.h>

// SSIM_13443247637111 — fused separable SSIM, V-first ring-buffer design.
// B=16, CH=3, 512x512, 11x11 gaussian sigma 1.5, zero padding 5.
//
// Round-13 structure (H x-blocking):
//  - ROUND-10 POST-MORTEM: hit (90.5us, conflicts 1.242e7, absmax 0).
//    LDS ledger (wave-insts/super): V-read 60, V-write 20, H-read 112,
//    stage 10 -> H is 55% of LDS traffic AND the 4-way even-bank conflict
//    source (f2 loads at even cols, even row stride).
//  - H X-BLOCKING (4 outputs/thread, 128 threads): 8 f2 loads per field for
//    4 outputs (was 14 for the same 4) -> H reads 112 -> 64 wave-insts
//    (-43%); total LDS/super -24%. Tap order per output stays ascending-k
//    (k = 2i-1-j for v.x, 2i-j for v.y, increasing in i) -> bit-identical.
//    Total fmaf unchanged; live set ~30 regs, fits (256,5)'s 48 cap.
//  - Frozen from R10: y-blocked V (160 thr, 12 reads), 4-field algebra,
//    premask, memset-init, LDS 22.9 KB, grid 8x8x48 = 3072.

#define BATCH 16
#define CHANS 3
#define IMH 512
#define IMW 512
#define STRIPW 64
#define STRIPH 64
#define RINGR 18            // raw rows resident: y-5 .. y+12 for an 8-row super
#define LDSW 84             // padded row width; col c <-> x = bx*64 + c - 8
#define SUP 8               // output rows per super-iteration
#define NSUP (STRIPH / SUP) // 8
#define NQ 20               // float4 quads per staged row (80 cols)

// mask-pass tile
#define MTW 64
#define MTH 64
#define MRAWH 74            // MTH + 10 halo rows

__device__ __forceinline__ float4 ld4s(const float* p) { return *(const float4*)p; }
__device__ __forceinline__ void st4s(float* p, float4 v) { *(float4*)p = v; }
__device__ __forceinline__ void fma4(float4& a, float w, float4 x) {
    a.x = fmaf(w, x.x, a.x); a.y = fmaf(w, x.y, a.y);
    a.z = fmaf(w, x.z, a.z); a.w = fmaf(w, x.w, a.w);
}
__device__ __forceinline__ void fma4m(float4& a, float w, float4 x, float4 y) {
    a.x = fmaf(w, x.x * y.x, a.x); a.y = fmaf(w, x.y * y.y, a.y);
    a.z = fmaf(w, x.z * y.z, a.z); a.w = fmaf(w, x.w * y.w, a.w);
}
__device__ __forceinline__ void add4(float4& a, float4 x) {
    a.x += x.x; a.y += x.y; a.z += x.z; a.w += x.w;
}
__device__ __forceinline__ void fma2(float2& a, float w, float2 x) {
    a.x = fmaf(w, x.x, a.x); a.y = fmaf(w, x.y, a.y);
}

// classic 20-float-window forms (mask_pass / fallback kernel only)
__device__ __forceinline__ void convg(const float* __restrict__ row, int cb,
                                      const float* __restrict__ g, float out[4]) {
    float w[20];
    #pragma unroll
    for (int i = 0; i < 5; ++i) {
        float4 v = ld4s(row + cb + 4 * i);
        w[4*i+0] = v.x; w[4*i+1] = v.y; w[4*i+2] = v.z; w[4*i+3] = v.w;
    }
    #pragma unroll
    for (int j = 0; j < 4; ++j) {
        float a = 0.0f;
        #pragma unroll
        for (int k = 0; k < 11; ++k) a = fmaf(g[k], w[3 + j + k], a);
        out[j] = a;
    }
}

__device__ __forceinline__ void convb(const float* __restrict__ row, int cb,
                                      float out[4]) {
    float w[20];
    #pragma unroll
    for (int i = 0; i < 5; ++i) {
        float4 v = ld4s(row + cb + 4 * i);
        w[4*i+0] = v.x; w[4*i+1] = v.y; w[4*i+2] = v.z; w[4*i+3] = v.w;
    }
    #pragma unroll
    for (int j = 0; j < 4; ++j) {
        float a = 0.0f;
        #pragma unroll
        for (int k = 0; k < 11; ++k) a += w[3 + j + k];
        out[j] = a;
    }
}

// ---------------------------------------------------------------------------
// mask precompute: box-filter match (11x11), threshold, store uint8 per pixel.
// Accumulates the full denominator sum(mask) into acc[1]; block (0,0,0)
// also writes the gaussian weight table.
// ---------------------------------------------------------------------------
__global__ __launch_bounds__(256) void mask_pass(
    const float* __restrict__ match, unsigned char* __restrict__ maskbuf,
    float* __restrict__ gw, double* __restrict__ acc)
{
    __shared__ __align__(16) float raw[MRAWH][LDSW];
    __shared__ __align__(16) float vs[MTH][LDSW];
    __shared__ float red[4];

    const int tid = threadIdx.x;
    const int b = blockIdx.z;
    const int x0 = blockIdx.x * MTW - 8;     // global x of LDS col 0 (aligned)
    const int y0 = blockIdx.y * MTH - 5;
    const float* pm = match + (size_t)b * (IMH * IMW);

    // one thread of one block writes the weight table (read only by the
    // LATER ssim_main_pm launch -> stream-order safe)
    if (tid == 0 && blockIdx.x == 0 && blockIdx.y == 0 && b == 0) {
        float t[11];
        float s = 0.0f;
        for (int i = 0; i < 11; ++i) {
            float d = (float)(i - 5);
            t[i] = expf(-(d * d) / 4.5f);
            s += t[i];
        }
        for (int i = 0; i < 11; ++i) gw[i] = t[i] / s;
    }

    // stage 74 rows x 20 quads (cols x0 .. x0+79), zero pad OOB
    for (int t = tid; t < MRAWH * NQ; t += 256) {
        int r = t / NQ, q = t - r * NQ;
        int gy = y0 + r;
        int gx = x0 + 4 * q;
        float4 v = make_float4(0.f, 0.f, 0.f, 0.f);
        if ((unsigned)gy < IMH) {
            if ((unsigned)gx <= (IMW - 4)) {
                v = ld4s(pm + gy * IMW + gx);
            } else {
                float tmp[4];
                #pragma unroll
                for (int e = 0; e < 4; ++e) {
                    int x = gx + e;
                    bool ok = (unsigned)x < IMW;
                    tmp[e] = ok ? pm[gy * IMW + x] : 0.0f;
                }
                v = make_float4(tmp[0], tmp[1], tmp[2], tmp[3]);
            }
        }
        st4s(&raw[r][4 * q], v);
    }
    __syncthreads();

    // vertical box: 64 rows x 20 quads
    for (int t = tid; t < MTH * NQ; t += 256) {
        int r = t / NQ, q = t - r * NQ;
        int cq = 4 * q;
        float4 a = make_float4(0.f, 0.f, 0.f, 0.f);
        #pragma unroll
        for (int k = 0; k < 11; ++k) add4(a, ld4s(&raw[r + k][cq]));
        st4s(&vs[r][cq], a);
    }
    __syncthreads();

    // horizontal box + threshold: 64 rows x 16 quads
    float den = 0.0f;
    for (int t = tid; t < MTH * 16; t += 256) {
        int r = t >> 4, q = t & 15;
        float mb[4];
        convb(vs[r], 4 * q, mb);
        unsigned char bits[4];
        #pragma unroll
        for (int j = 0; j < 4; ++j) {
            float m = mb[j] * (1.0f / 121.0f) + 1e-7f;
            bool on = m > 0.5f;
            bits[j] = (unsigned char)on;
            den += on ? (1.0f + 1e-7f) : 1e-7f;
        }
        int gy = blockIdx.y * MTH + r;
        int gx = blockIdx.x * MTW + 4 * q;
        *(uchar4*)(maskbuf + ((size_t)b << 18) + (gy << 9) + gx) =
            make_uchar4(bits[0], bits[1], bits[2], bits[3]);
    }

    for (int off = 32; off > 0; off >>= 1) den += __shfl_down(den, off);
    if ((tid & 63) == 0) red[tid >> 6] = den;
    __syncthreads();
    if (tid == 0)
        atomicAdd(&acc[1], (double)(red[0] + red[1] + red[2] + red[3]));
}

// ---------------------------------------------------------------------------
// main SSIM kernel: 2 rings + 4 fld arrays (A,B,S,P), LDS 22.9 KB.
// V phase: y-blocked, 160 threads x (2 rows x f2 col-pair), 12 reads/thread.
// H phase: x-blocked, 128 threads x 4 outputs, 8 f2 loads per field.
// __launch_bounds__(256,5). Grid 8x8x48.
// ---------------------------------------------------------------------------
__global__ __launch_bounds__(256, 5) void ssim_main_pm(
    const float* __restrict__ img1, const float* __restrict__ img2,
    const unsigned char* __restrict__ maskbuf,
    const float* __restrict__ gw, double* __restrict__ acc)
{
    __shared__ __align__(16) float ring1[RINGR][LDSW];
    __shared__ __align__(16) float ring2[RINGR][LDSW];
    __shared__ __align__(16) float fld[4][SUP][LDSW];
    __shared__ float redn[4];

    const int tid = threadIdx.x;
    const int bc = blockIdx.z;
    const int b = bc / CHANS;
    const int c = bc - b * CHANS;
    const int ystart = blockIdx.y * STRIPH;
    const int bxg = blockIdx.x;
    const int bx0 = bxg * STRIPW - 8;   // global x of LDS col 0

    const float* p1 = img1 + (size_t)(b * CHANS + c) * (IMH * IMW);
    const float* p2 = img2 + (size_t)(b * CHANS + c) * (IMH * IMW);
    const unsigned char* pmk = maskbuf + ((size_t)b << 18);

    // weights: uniform pointer + constant offsets -> scalar loads (SGPRs)
    float g[11];
    #pragma unroll
    for (int i = 0; i < 11; ++i) g[i] = gw[i];

    float num = 0.0f;
    const bool colsafe = (bx0 >= 0) && (bx0 + 4 * NQ <= IMW);  // interior in x

    auto stage = [&](int gy0, int nrows) {
        // nrows*NQ <= 200 < 256: single shot, no loop
        if (tid < nrows * NQ) {
            int r = tid / NQ, q = tid - r * NQ;
            int gy = gy0 + r;
            int slot = (gy + 36) % RINGR;
            int gx = bx0 + 4 * q;
            float4 v1 = make_float4(0.f, 0.f, 0.f, 0.f), v2 = v1;
            if ((unsigned)gy < IMH) {
                if (colsafe || (unsigned)gx <= (IMW - 4)) {
                    v1 = ld4s(p1 + gy * IMW + gx);
                    v2 = ld4s(p2 + gy * IMW + gx);
                } else {
                    float t1[4], t2[4];
                    #pragma unroll
                    for (int e = 0; e < 4; ++e) {
                        int x = gx + e;
                        bool ok = (unsigned)x < IMW;
                        int off = gy * IMW + (ok ? x : 0);
                        t1[e] = ok ? p1[off] : 0.0f;
                        t2[e] = ok ? p2[off] : 0.0f;
                    }
                    v1 = make_float4(t1[0], t1[1], t1[2], t1[3]);
                    v2 = make_float4(t2[0], t2[1], t2[2], t2[3]);
                }
            }
            st4s(&ring1[slot][4 * q], v1);
            st4s(&ring2[slot][4 * q], v2);
        }
    };

    // prologue: raw rows ystart-5 .. ystart+4
    stage(ystart - 5, 10);

    for (int s = 0; s < NSUP; ++s) {
        const int ybase = ystart + s * SUP;

        // stage the 8 new raw rows this super needs (ybase+5 .. ybase+12).
        stage(ybase + 5, SUP);
        __syncthreads();   // B1: staging visible; fld free (H of s-1 done)

        // ---- vertical pass: y-blocked, 160 threads ----
        // thread -> (rb, hq): rb = tid/40 in 0..3 owns output rows
        // ybase+2rb, ybase+2rb+1 for col-pair hq. Reads the 12 contributing
        // ring rows once each; static weight indexing (fully unrolled):
        //   out0 taps t=0..10 with g[t]; out1 taps t=1..11 with g[t-1].
        if (tid < 160) {
            const int rb = tid / 40;
            const int hq = tid - rb * 40;
            const int cw = 2 * hq;
            const int r0 = 2 * rb;               // local output row index
            int sr = (ybase + r0 + 31) % RINGR;  // absolute row (y0 - 5)
            float2 z = make_float2(0.f, 0.f);
            float2 A0 = z, B0 = z, S0 = z, P0 = z;
            float2 A1 = z, B1 = z, S1 = z, P1 = z;
            #pragma unroll
            for (int t = 0; t < 12; ++t) {
                float2 x1 = *(const float2*)&ring1[sr][cw];
                float2 x2 = *(const float2*)&ring2[sr][cw];
                float2 sv, pv;
                sv.x = fmaf(x2.x, x2.x, x1.x * x1.x);
                sv.y = fmaf(x2.y, x2.y, x1.y * x1.y);
                pv.x = x1.x * x2.x;
                pv.y = x1.y * x2.y;
                if (t <= 10) {
                    float w = g[t];
                    fma2(A0, w, x1); fma2(B0, w, x2);
                    fma2(S0, w, sv); fma2(P0, w, pv);
                }
                if (t >= 1) {
                    float w = g[t - 1];
                    fma2(A1, w, x1); fma2(B1, w, x2);
                    fma2(S1, w, sv); fma2(P1, w, pv);
                }
                sr++; if (sr >= RINGR) sr -= RINGR;
            }
            *(float2*)&fld[0][r0][cw] = A0; *(float2*)&fld[0][r0 + 1][cw] = A1;
            *(float2*)&fld[1][r0][cw] = B0; *(float2*)&fld[1][r0 + 1][cw] = B1;
            *(float2*)&fld[2][r0][cw] = S0; *(float2*)&fld[2][r0 + 1][cw] = S1;
            *(float2*)&fld[3][r0][cw] = P0; *(float2*)&fld[3][r0 + 1][cw] = P1;
        }
        __syncthreads();   // B2: fld visible; ring free for next stage

        // ---- horizontal pass + SSIM: x-blocked, 8 rows x 16 col-quads ----
        // thread (r = tid>>4, h = tid&15) produces outputs at strip cols
        // 4h..4h+3 (LDS cols 4h+8..4h+11). Taps span LDS cols 4h+3..4h+16;
        // loaded as 8 f2 starting at c0 = 4h+2 (8B aligned). For load i:
        //   v.x is tap t=2i   -> output j gets k = 2i-1-j (if 0<=k<=10)
        //   v.y is tap t=2i+1 -> output j gets k = 2i-j   (if 0<=k<=10)
        // Per output, k increases over i, v.x before v.y -> ascending-k
        // order == classic convg -> bit-identical.
        if (tid < SUP * 16) {
            int r = tid >> 4, h = tid & 15;
            const int c0 = 4 * h + 2;   // loads cols c0 .. c0+15
            float mu1[4], mu2[4], hS[4], hP[4];
            auto convg4x = [&](const float* __restrict__ row, float out[4]) {
                float a0 = 0.0f, a1 = 0.0f, a2 = 0.0f, a3 = 0.0f;
                #pragma unroll
                for (int i = 0; i < 8; ++i) {
                    float2 v = *(const float2*)(row + c0 + 2 * i);
                    // j = 0
                    { const int kx = 2*i - 1; const int ky = 2*i;
                      if (kx >= 0 && kx <= 10) a0 = fmaf(g[kx], v.x, a0);
                      if (ky >= 0 && ky <= 10) a0 = fmaf(g[ky], v.y, a0); }
                    // j = 1
                    { const int kx = 2*i - 2; const int ky = 2*i - 1;
                      if (kx >= 0 && kx <= 10) a1 = fmaf(g[kx], v.x, a1);
                      if (ky >= 0 && ky <= 10) a1 = fmaf(g[ky], v.y, a1); }
                    // j = 2
                    { const int kx = 2*i - 3; const int ky = 2*i - 2;
                      if (kx >= 0 && kx <= 10) a2 = fmaf(g[kx], v.x, a2);
                      if (ky >= 0 && ky <= 10) a2 = fmaf(g[ky], v.y, a2); }
                    // j = 3
                    { const int kx = 2*i - 4; const int ky = 2*i - 3;
                      if (kx >= 0 && kx <= 10) a3 = fmaf(g[kx], v.x, a3);
                      if (ky >= 0 && ky <= 10) a3 = fmaf(g[ky], v.y, a3); }
                }
                out[0] = a0; out[1] = a1; out[2] = a2; out[3] = a3;
            };
            convg4x(fld[0][r], mu1);
            convg4x(fld[1][r], mu2);
            convg4x(fld[2][r], hS);
            convg4x(fld[3][r], hP);

            int gy = ybase + r;
            int gx = bxg * STRIPW + 4 * h;
            uchar4 mk = *(const uchar4*)(pmk + (gy << 9) + gx);
            const unsigned char mkv[4] = {mk.x, mk.y, mk.z, mk.w};
            #pragma unroll
            for (int j = 0; j < 4; ++j) {
                float mu1s = mu1[j] * mu1[j];
                float mu2s = mu2[j] * mu2[j];
                float mu12 = mu1[j] * mu2[j];
                float sgsum = hS[j] - mu1s - mu2s;   // sigma1_sq + sigma2_sq
                float sg12  = hP[j] - mu12;          // sigma12
                float ssim = ((2.0f * mu12 + 1e-4f) * (2.0f * sg12 + 9e-4f)) /
                             ((mu1s + mu2s + 1e-4f) * (sgsum + 9e-4f));
                float mask = mkv[j] ? (1.0f + 1e-7f) : 1e-7f;
                num += (1.0f - ssim) * mask;
            }
        }
    }

    // ---- block reduction: wave shuffle (width 64) then cross-wave LDS ----
    for (int off = 32; off > 0; off >>= 1) num += __shfl_down(num, off);
    if ((tid & 63) == 0) redn[tid >> 6] = num;
    __syncthreads();
    if (tid == 0)
        atomicAdd(&acc[0], (double)(redn[0] + redn[1] + redn[2] + redn[3]));
    (void)c;
}

// ---------------------------------------------------------------------------
// fallback: round-2 all-in-one kernel (used only if ws too small for mask)
// ---------------------------------------------------------------------------
#define FBSTRIPH 256
#define FBNSUP (FBSTRIPH / SUP)
__global__ __launch_bounds__(256) void ssim_main_fb(
    const float* __restrict__ img1, const float* __restrict__ img2,
    const float* __restrict__ match, double* __restrict__ acc)
{
    __shared__ __align__(16) float ring1[RINGR][LDSW];
    __shared__ __align__(16) float ring2[RINGR][LDSW];
    __shared__ __align__(16) float ringm[RINGR][LDSW];
    __shared__ __align__(16) float fld[6][SUP][LDSW];
    __shared__ float redn[4], redd[4];

    const int tid = threadIdx.x;
    const int bc = blockIdx.z;
    const int b = bc / CHANS;
    const int c = bc - b * CHANS;
    const int ystart = blockIdx.y * FBSTRIPH;
    const int bx0 = blockIdx.x * STRIPW - 8;

    const float* p1 = img1 + (size_t)(b * CHANS + c) * (IMH * IMW);
    const float* p2 = img2 + (size_t)(b * CHANS + c) * (IMH * IMW);
    const float* pm = match + (size_t)b * (IMH * IMW);

    float g[11];
    {
        float s = 0.0f;
        #pragma unroll
        for (int i = 0; i < 11; ++i) {
            float d = (float)(i - 5);
            g[i] = expf(-(d * d) / 4.5f);
            s += g[i];
        }
        #pragma unroll
        for (int i = 0; i < 11; ++i) g[i] /= s;
    }

    float num = 0.0f, den = 0.0f;

    auto stage = [&](int gy0, int nrows) {
        for (int t = tid; t < nrows * NQ; t += 256) {
            int r = t / NQ, q = t - r * NQ;
            int gy = gy0 + r;
            int slot = (gy + 36) % RINGR;
            int gx = bx0 + 4 * q;
            float4 v1, v2, vm;
            if ((unsigned)gy < IMH && (unsigned)gx <= (IMW - 4)) {
                v1 = ld4s(p1 + gy * IMW + gx);
                v2 = ld4s(p2 + gy * IMW + gx);
                vm = ld4s(pm + gy * IMW + gx);
            } else if ((unsigned)gy < IMH) {
                float t1[4], t2[4], tm[4];
                #pragma unroll
                for (int e = 0; e < 4; ++e) {
                    int x = gx + e;
                    bool ok = (unsigned)x < IMW;
                    int off = gy * IMW + (ok ? x : 0);
                    t1[e] = ok ? p1[off] : 0.0f;
                    t2[e] = ok ? p2[off] : 0.0f;
                    tm[e] = ok ? pm[off] : 0.0f;
                }
                v1 = make_float4(t1[0], t1[1], t1[2], t1[3]);
                v2 = make_float4(t2[0], t2[1], t2[2], t2[3]);
                vm = make_float4(tm[0], tm[1], tm[2], tm[3]);
            } else {
                v1 = v2 = vm = make_float4(0.f, 0.f, 0.f, 0.f);
            }
            st4s(&ring1[slot][4 * q], v1);
            st4s(&ring2[slot][4 * q], v2);
            st4s(&ringm[slot][4 * q], vm);
        }
    };

    stage(ystart - 5, 10);

    for (int s = 0; s < FBNSUP; ++s) {
        const int ybase = ystart + s * SUP;
        stage(ybase + 5, SUP);
        __syncthreads();

        if (tid < SUP * NQ) {
            int r = tid / NQ, q = tid - r * NQ;
            int cq = 4 * q;
            int sr = (ybase + r + 31) % RINGR;
            float4 a1 = make_float4(0,0,0,0), a2 = a1, a3 = a1,
                   a4 = a1, a5 = a1, am = a1;
            #pragma unroll
            for (int k = 0; k < 11; ++k) {
                float4 x1 = ld4s(&ring1[sr][cq]);
                float4 x2 = ld4s(&ring2[sr][cq]);
                float4 xm = ld4s(&ringm[sr][cq]);
                float w = g[k];
                fma4(a1, w, x1);
                fma4(a2, w, x2);
                fma4m(a3, w, x1, x1);
                fma4m(a4, w, x2, x2);
                fma4m(a5, w, x1, x2);
                add4(am, xm);
                sr++; if (sr >= RINGR) sr -= RINGR;
            }
            st4s(&fld[0][r][cq], a1);
            st4s(&fld[1][r][cq], a2);
            st4s(&fld[2][r][cq], a3);
            st4s(&fld[3][r][cq], a4);
            st4s(&fld[4][r][cq], a5);
            st4s(&fld[5][r][cq], am);
        }
        __syncthreads();

        if (tid < SUP * 16) {
            int r = tid >> 4, q = tid & 15;
            int cb = 4 * q;
            float mu1[4], mu2[4], m11[4], m22[4], m12[4], mb[4];
            convg(fld[0][r], cb, g, mu1);
            convg(fld[1][r], cb, g, mu2);
            convg(fld[2][r], cb, g, m11);
            convg(fld[3][r], cb, g, m22);
            convg(fld[4][r], cb, g, m12);
            convb(fld[5][r], cb, mb);
            #pragma unroll
            for (int j = 0; j < 4; ++j) {
                float mu1s = mu1[j] * mu1[j];
                float mu2s = mu2[j] * mu2[j];
                float mu12 = mu1[j] * mu2[j];
                float sg1  = m11[j] - mu1s;
                float sg2  = m22[j] - mu2s;
                float sg12 = m12[j] - mu12;
                float ssim = ((2.0f * mu12 + 1e-4f) * (2.0f * sg12 + 9e-4f)) /
                             ((mu1s + mu2s + 1e-4f) * (sg1 + sg2 + 9e-4f));
                float m = mb[j] * (1.0f / 121.0f) + 1e-7f;
                float mask = (m > 0.5f) ? (1.0f + 1e-7f) : 1e-7f;
                num += (1.0f - ssim) * mask;
                den += mask;
            }
        }
    }

    for (int off = 32; off > 0; off >>= 1) {
        num += __shfl_down(num, off);
        den += __shfl_down(den, off);
    }
    int wave = tid >> 6;
    int lane = tid & 63;
    if (lane == 0) { redn[wave] = num; redd[wave] = den; }
    __syncthreads();
    if (tid == 0) {
        float n = redn[0] + redn[1] + redn[2] + redn[3];
        atomicAdd(&acc[0], (double)n);
        if (c == 0) {
            float d = redd[0] + redd[1] + redd[2] + redd[3];
            atomicAdd(&acc[1], (double)d);
        }
    }
}

__global__ void finalize(const double* __restrict__ acc, float* __restrict__ out) {
    out[0] = (float)(acc[0] / acc[1] / 3.0);
}

extern "C" void kernel_launch(void* const* d_in, const int* in_sizes, int n_in,
                              void* d_out, int out_size, void* d_ws, size_t ws_size,
                              hipStream_t stream) {
    const float* img1  = (const float*)d_in[0];
    const float* img2  = (const float*)d_in[1];
    const float* match = (const float*)d_in[2];
    float* out = (float*)d_out;
    double* acc = (double*)d_ws;                       // 16 B @ ws+0

    const size_t mask_need = 128 + (size_t)BATCH * IMH * IMW;  // 4,194,432 B
    const bool premask = (ws_size >= mask_need);
    float* gw = (float*)((char*)d_ws + 64);            // 44 B @ ws+64

    // zero acc[0..1] (doubles: all-zero bytes == +0.0); capturable async op
    hipMemsetAsync(d_ws, 0, 16, stream);

    dim3 block(256, 1, 1);
    if (premask) {
        unsigned char* mbuf = (unsigned char*)d_ws + 128;
        dim3 mgrid(IMW / MTW, IMH / MTH, BATCH);               // 8 x 8 x 16
        mask_pass<<<mgrid, block, 0, stream>>>(match, mbuf, gw, acc);
        dim3 grid(IMW / STRIPW, IMH / STRIPH, BATCH * CHANS);  // 8 x 8 x 48
        ssim_main_pm<<<grid, block, 0, stream>>>(img1, img2, mbuf, gw, acc);
    } else {
        dim3 grid(IMW / STRIPW, IMH / FBSTRIPH, BATCH * CHANS);
        ssim_main_fb<<<grid, block, 0, stream>>>(img1, img2, match, acc);
    }

    finalize<<<1, 1, 0, stream>>>(acc, out);
}

// Round 12
// 211.637 us; speedup vs baseline: 1.0499x; 1.0499x over previous
//
#include <hip/hip_runtime.h>

// SSIM_13443247637111 — fused separable SSIM, V-first ring-buffer design.
// B=16, CH=3, 512x512, 11x11 gaussian sigma 1.5, zero padding 5.
//
// Round-14 = Round-12 (90.5us proven) REVERT + s_setprio around compute.
//  - ROUND-13 POST-MORTEM: H x-blocking REGRESSED (90.5->103): spilled
//    (WRITE 6 MB; 16-acc live set > 48 cap), conflicts +0.5e7 (stride-16B
//    f2 worse, not better), and concentrating H onto 128 threads doubled
//    the per-wave inter-barrier critical path (~10us). Rule refined: only
//    "fewer per-thread LDS insts, SAME patterns, NO work concentration"
//    wins (4/4 hits); every pattern/concentration change lost (0/3).
//  - This round: exact R10 kernel + __builtin_amdgcn_s_setprio(1/0)
//    around V and H compute (catalog T5): ~4.6 staggered blocks/CU give
//    wave role diversity (FMA-phase vs stage-phase waves across blocks);
//    priority keeps compute waves fed. Zero correctness risk,
//    pattern-identical, bit-identical output.
//  - Frozen: y-blocked V (160 thr, 12 reads), f2-H streaming (256 thr),
//    4-field algebra, premask, memset-init, LDS 22.9 KB, (256,5),
//    grid 8x8x48 = 3072.

#define BATCH 16
#define CHANS 3
#define IMH 512
#define IMW 512
#define STRIPW 64
#define STRIPH 64
#define RINGR 18            // raw rows resident: y-5 .. y+12 for an 8-row super
#define LDSW 84             // padded row width; col c <-> x = bx*64 + c - 8
#define SUP 8               // output rows per super-iteration
#define NSUP (STRIPH / SUP) // 8
#define NQ 20               // float4 quads per staged row (80 cols)

// mask-pass tile
#define MTW 64
#define MTH 64
#define MRAWH 74            // MTH + 10 halo rows

__device__ __forceinline__ float4 ld4s(const float* p) { return *(const float4*)p; }
__device__ __forceinline__ void st4s(float* p, float4 v) { *(float4*)p = v; }
__device__ __forceinline__ void fma4(float4& a, float w, float4 x) {
    a.x = fmaf(w, x.x, a.x); a.y = fmaf(w, x.y, a.y);
    a.z = fmaf(w, x.z, a.z); a.w = fmaf(w, x.w, a.w);
}
__device__ __forceinline__ void fma4m(float4& a, float w, float4 x, float4 y) {
    a.x = fmaf(w, x.x * y.x, a.x); a.y = fmaf(w, x.y * y.y, a.y);
    a.z = fmaf(w, x.z * y.z, a.z); a.w = fmaf(w, x.w * y.w, a.w);
}
__device__ __forceinline__ void add4(float4& a, float4 x) {
    a.x += x.x; a.y += x.y; a.z += x.z; a.w += x.w;
}
__device__ __forceinline__ void fma2(float2& a, float w, float2 x) {
    a.x = fmaf(w, x.x, a.x); a.y = fmaf(w, x.y, a.y);
}

// classic 20-float-window forms (mask_pass / fallback kernel only)
__device__ __forceinline__ void convg(const float* __restrict__ row, int cb,
                                      const float* __restrict__ g, float out[4]) {
    float w[20];
    #pragma unroll
    for (int i = 0; i < 5; ++i) {
        float4 v = ld4s(row + cb + 4 * i);
        w[4*i+0] = v.x; w[4*i+1] = v.y; w[4*i+2] = v.z; w[4*i+3] = v.w;
    }
    #pragma unroll
    for (int j = 0; j < 4; ++j) {
        float a = 0.0f;
        #pragma unroll
        for (int k = 0; k < 11; ++k) a = fmaf(g[k], w[3 + j + k], a);
        out[j] = a;
    }
}

__device__ __forceinline__ void convb(const float* __restrict__ row, int cb,
                                      float out[4]) {
    float w[20];
    #pragma unroll
    for (int i = 0; i < 5; ++i) {
        float4 v = ld4s(row + cb + 4 * i);
        w[4*i+0] = v.x; w[4*i+1] = v.y; w[4*i+2] = v.z; w[4*i+3] = v.w;
    }
    #pragma unroll
    for (int j = 0; j < 4; ++j) {
        float a = 0.0f;
        #pragma unroll
        for (int k = 0; k < 11; ++k) a += w[3 + j + k];
        out[j] = a;
    }
}

// ---------------------------------------------------------------------------
// mask precompute: box-filter match (11x11), threshold, store uint8 per pixel.
// Accumulates the full denominator sum(mask) into acc[1]; block (0,0,0)
// also writes the gaussian weight table.
// ---------------------------------------------------------------------------
__global__ __launch_bounds__(256) void mask_pass(
    const float* __restrict__ match, unsigned char* __restrict__ maskbuf,
    float* __restrict__ gw, double* __restrict__ acc)
{
    __shared__ __align__(16) float raw[MRAWH][LDSW];
    __shared__ __align__(16) float vs[MTH][LDSW];
    __shared__ float red[4];

    const int tid = threadIdx.x;
    const int b = blockIdx.z;
    const int x0 = blockIdx.x * MTW - 8;     // global x of LDS col 0 (aligned)
    const int y0 = blockIdx.y * MTH - 5;
    const float* pm = match + (size_t)b * (IMH * IMW);

    // one thread of one block writes the weight table (read only by the
    // LATER ssim_main_pm launch -> stream-order safe)
    if (tid == 0 && blockIdx.x == 0 && blockIdx.y == 0 && b == 0) {
        float t[11];
        float s = 0.0f;
        for (int i = 0; i < 11; ++i) {
            float d = (float)(i - 5);
            t[i] = expf(-(d * d) / 4.5f);
            s += t[i];
        }
        for (int i = 0; i < 11; ++i) gw[i] = t[i] / s;
    }

    // stage 74 rows x 20 quads (cols x0 .. x0+79), zero pad OOB
    for (int t = tid; t < MRAWH * NQ; t += 256) {
        int r = t / NQ, q = t - r * NQ;
        int gy = y0 + r;
        int gx = x0 + 4 * q;
        float4 v = make_float4(0.f, 0.f, 0.f, 0.f);
        if ((unsigned)gy < IMH) {
            if ((unsigned)gx <= (IMW - 4)) {
                v = ld4s(pm + gy * IMW + gx);
            } else {
                float tmp[4];
                #pragma unroll
                for (int e = 0; e < 4; ++e) {
                    int x = gx + e;
                    bool ok = (unsigned)x < IMW;
                    tmp[e] = ok ? pm[gy * IMW + x] : 0.0f;
                }
                v = make_float4(tmp[0], tmp[1], tmp[2], tmp[3]);
            }
        }
        st4s(&raw[r][4 * q], v);
    }
    __syncthreads();

    // vertical box: 64 rows x 20 quads
    for (int t = tid; t < MTH * NQ; t += 256) {
        int r = t / NQ, q = t - r * NQ;
        int cq = 4 * q;
        float4 a = make_float4(0.f, 0.f, 0.f, 0.f);
        #pragma unroll
        for (int k = 0; k < 11; ++k) add4(a, ld4s(&raw[r + k][cq]));
        st4s(&vs[r][cq], a);
    }
    __syncthreads();

    // horizontal box + threshold: 64 rows x 16 quads
    float den = 0.0f;
    for (int t = tid; t < MTH * 16; t += 256) {
        int r = t >> 4, q = t & 15;
        float mb[4];
        convb(vs[r], 4 * q, mb);
        unsigned char bits[4];
        #pragma unroll
        for (int j = 0; j < 4; ++j) {
            float m = mb[j] * (1.0f / 121.0f) + 1e-7f;
            bool on = m > 0.5f;
            bits[j] = (unsigned char)on;
            den += on ? (1.0f + 1e-7f) : 1e-7f;
        }
        int gy = blockIdx.y * MTH + r;
        int gx = blockIdx.x * MTW + 4 * q;
        *(uchar4*)(maskbuf + ((size_t)b << 18) + (gy << 9) + gx) =
            make_uchar4(bits[0], bits[1], bits[2], bits[3]);
    }

    for (int off = 32; off > 0; off >>= 1) den += __shfl_down(den, off);
    if ((tid & 63) == 0) red[tid >> 6] = den;
    __syncthreads();
    if (tid == 0)
        atomicAdd(&acc[1], (double)(red[0] + red[1] + red[2] + red[3]));
}

// ---------------------------------------------------------------------------
// main SSIM kernel: 2 rings + 4 fld arrays (A,B,S,P), LDS 22.9 KB.
// V phase: y-blocked, 160 threads x (2 rows x f2 col-pair), 12 reads/thread.
// H phase: f2 streaming, 256 threads x 2 outputs. s_setprio(1) around both
// compute phases (T5). __launch_bounds__(256,5). Grid 8x8x48.
// ---------------------------------------------------------------------------
__global__ __launch_bounds__(256, 5) void ssim_main_pm(
    const float* __restrict__ img1, const float* __restrict__ img2,
    const unsigned char* __restrict__ maskbuf,
    const float* __restrict__ gw, double* __restrict__ acc)
{
    __shared__ __align__(16) float ring1[RINGR][LDSW];
    __shared__ __align__(16) float ring2[RINGR][LDSW];
    __shared__ __align__(16) float fld[4][SUP][LDSW];
    __shared__ float redn[4];

    const int tid = threadIdx.x;
    const int bc = blockIdx.z;
    const int b = bc / CHANS;
    const int c = bc - b * CHANS;
    const int ystart = blockIdx.y * STRIPH;
    const int bxg = blockIdx.x;
    const int bx0 = bxg * STRIPW - 8;   // global x of LDS col 0

    const float* p1 = img1 + (size_t)(b * CHANS + c) * (IMH * IMW);
    const float* p2 = img2 + (size_t)(b * CHANS + c) * (IMH * IMW);
    const unsigned char* pmk = maskbuf + ((size_t)b << 18);

    // weights: uniform pointer + constant offsets -> scalar loads (SGPRs)
    float g[11];
    #pragma unroll
    for (int i = 0; i < 11; ++i) g[i] = gw[i];

    float num = 0.0f;
    const bool colsafe = (bx0 >= 0) && (bx0 + 4 * NQ <= IMW);  // interior in x

    auto stage = [&](int gy0, int nrows) {
        // nrows*NQ <= 200 < 256: single shot, no loop
        if (tid < nrows * NQ) {
            int r = tid / NQ, q = tid - r * NQ;
            int gy = gy0 + r;
            int slot = (gy + 36) % RINGR;
            int gx = bx0 + 4 * q;
            float4 v1 = make_float4(0.f, 0.f, 0.f, 0.f), v2 = v1;
            if ((unsigned)gy < IMH) {
                if (colsafe || (unsigned)gx <= (IMW - 4)) {
                    v1 = ld4s(p1 + gy * IMW + gx);
                    v2 = ld4s(p2 + gy * IMW + gx);
                } else {
                    float t1[4], t2[4];
                    #pragma unroll
                    for (int e = 0; e < 4; ++e) {
                        int x = gx + e;
                        bool ok = (unsigned)x < IMW;
                        int off = gy * IMW + (ok ? x : 0);
                        t1[e] = ok ? p1[off] : 0.0f;
                        t2[e] = ok ? p2[off] : 0.0f;
                    }
                    v1 = make_float4(t1[0], t1[1], t1[2], t1[3]);
                    v2 = make_float4(t2[0], t2[1], t2[2], t2[3]);
                }
            }
            st4s(&ring1[slot][4 * q], v1);
            st4s(&ring2[slot][4 * q], v2);
        }
    };

    // prologue: raw rows ystart-5 .. ystart+4
    stage(ystart - 5, 10);

    for (int s = 0; s < NSUP; ++s) {
        const int ybase = ystart + s * SUP;

        // stage the 8 new raw rows this super needs (ybase+5 .. ybase+12).
        stage(ybase + 5, SUP);
        __syncthreads();   // B1: staging visible; fld free (H of s-1 done)

        // ---- vertical pass: y-blocked, 160 threads ----
        // thread -> (rb, hq): rb = tid/40 in 0..3 owns output rows
        // ybase+2rb, ybase+2rb+1 for col-pair hq. Reads the 12 contributing
        // ring rows once each; static weight indexing (fully unrolled):
        //   out0 taps t=0..10 with g[t]; out1 taps t=1..11 with g[t-1].
        if (tid < 160) {
            __builtin_amdgcn_s_setprio(1);
            const int rb = tid / 40;
            const int hq = tid - rb * 40;
            const int cw = 2 * hq;
            const int r0 = 2 * rb;               // local output row index
            int sr = (ybase + r0 + 31) % RINGR;  // absolute row (y0 - 5)
            float2 z = make_float2(0.f, 0.f);
            float2 A0 = z, B0 = z, S0 = z, P0 = z;
            float2 A1 = z, B1 = z, S1 = z, P1 = z;
            #pragma unroll
            for (int t = 0; t < 12; ++t) {
                float2 x1 = *(const float2*)&ring1[sr][cw];
                float2 x2 = *(const float2*)&ring2[sr][cw];
                float2 sv, pv;
                sv.x = fmaf(x2.x, x2.x, x1.x * x1.x);
                sv.y = fmaf(x2.y, x2.y, x1.y * x1.y);
                pv.x = x1.x * x2.x;
                pv.y = x1.y * x2.y;
                if (t <= 10) {
                    float w = g[t];
                    fma2(A0, w, x1); fma2(B0, w, x2);
                    fma2(S0, w, sv); fma2(P0, w, pv);
                }
                if (t >= 1) {
                    float w = g[t - 1];
                    fma2(A1, w, x1); fma2(B1, w, x2);
                    fma2(S1, w, sv); fma2(P1, w, pv);
                }
                sr++; if (sr >= RINGR) sr -= RINGR;
            }
            *(float2*)&fld[0][r0][cw] = A0; *(float2*)&fld[0][r0 + 1][cw] = A1;
            *(float2*)&fld[1][r0][cw] = B0; *(float2*)&fld[1][r0 + 1][cw] = B1;
            *(float2*)&fld[2][r0][cw] = S0; *(float2*)&fld[2][r0 + 1][cw] = S1;
            *(float2*)&fld[3][r0][cw] = P0; *(float2*)&fld[3][r0 + 1][cw] = P1;
            __builtin_amdgcn_s_setprio(0);
        }
        __syncthreads();   // B2: fld visible; ring free for next stage

        // ---- horizontal pass + SSIM: 8 rows x 32 float2 cols, 256 thr ----
        // STREAMING form: 7 float2 loads per field, ascending-k per output.
        {
            __builtin_amdgcn_s_setprio(1);
            int r = tid >> 5, h = tid & 31;
            const int c0 = 2 * h + 2;   // loads cols c0 .. c0+13
            float mu1[2], mu2[2], hS[2], hP[2];
            auto convg2s = [&](const float* __restrict__ row, float out[2]) {
                float a0 = 0.0f, a1 = 0.0f;
                #pragma unroll
                for (int i = 0; i < 7; ++i) {
                    float2 v = *(const float2*)(row + c0 + 2 * i);
                    // out0 taps: cols c0+1..c0+11 (k = j-1, j = col-c0)
                    // out1 taps: cols c0+2..c0+12 (k = j-2)
                    if (i >= 1 && i <= 5) a0 = fmaf(g[2*i-1], v.x, a0);
                    if (i <= 5)           a0 = fmaf(g[2*i],   v.y, a0);
                    if (i >= 1)           a1 = fmaf(g[2*i-2], v.x, a1);
                    if (i >= 1 && i <= 5) a1 = fmaf(g[2*i-1], v.y, a1);
                }
                out[0] = a0; out[1] = a1;
            };
            convg2s(fld[0][r], mu1);
            convg2s(fld[1][r], mu2);
            convg2s(fld[2][r], hS);
            convg2s(fld[3][r], hP);

            int gy = ybase + r;
            int gx = bxg * STRIPW + 2 * h;
            uchar2 mk = *(const uchar2*)(pmk + (gy << 9) + gx);
            const unsigned char mkv[2] = {mk.x, mk.y};
            #pragma unroll
            for (int j = 0; j < 2; ++j) {
                float mu1s = mu1[j] * mu1[j];
                float mu2s = mu2[j] * mu2[j];
                float mu12 = mu1[j] * mu2[j];
                float sgsum = hS[j] - mu1s - mu2s;   // sigma1_sq + sigma2_sq
                float sg12  = hP[j] - mu12;          // sigma12
                float ssim = ((2.0f * mu12 + 1e-4f) * (2.0f * sg12 + 9e-4f)) /
                             ((mu1s + mu2s + 1e-4f) * (sgsum + 9e-4f));
                float mask = mkv[j] ? (1.0f + 1e-7f) : 1e-7f;
                num += (1.0f - ssim) * mask;
            }
            __builtin_amdgcn_s_setprio(0);
        }
    }

    // ---- block reduction: wave shuffle (width 64) then cross-wave LDS ----
    for (int off = 32; off > 0; off >>= 1) num += __shfl_down(num, off);
    if ((tid & 63) == 0) redn[tid >> 6] = num;
    __syncthreads();
    if (tid == 0)
        atomicAdd(&acc[0], (double)(redn[0] + redn[1] + redn[2] + redn[3]));
    (void)c;
}

// ---------------------------------------------------------------------------
// fallback: round-2 all-in-one kernel (used only if ws too small for mask)
// ---------------------------------------------------------------------------
#define FBSTRIPH 256
#define FBNSUP (FBSTRIPH / SUP)
__global__ __launch_bounds__(256) void ssim_main_fb(
    const float* __restrict__ img1, const float* __restrict__ img2,
    const float* __restrict__ match, double* __restrict__ acc)
{
    __shared__ __align__(16) float ring1[RINGR][LDSW];
    __shared__ __align__(16) float ring2[RINGR][LDSW];
    __shared__ __align__(16) float ringm[RINGR][LDSW];
    __shared__ __align__(16) float fld[6][SUP][LDSW];
    __shared__ float redn[4], redd[4];

    const int tid = threadIdx.x;
    const int bc = blockIdx.z;
    const int b = bc / CHANS;
    const int c = bc - b * CHANS;
    const int ystart = blockIdx.y * FBSTRIPH;
    const int bx0 = blockIdx.x * STRIPW - 8;

    const float* p1 = img1 + (size_t)(b * CHANS + c) * (IMH * IMW);
    const float* p2 = img2 + (size_t)(b * CHANS + c) * (IMH * IMW);
    const float* pm = match + (size_t)b * (IMH * IMW);

    float g[11];
    {
        float s = 0.0f;
        #pragma unroll
        for (int i = 0; i < 11; ++i) {
            float d = (float)(i - 5);
            g[i] = expf(-(d * d) / 4.5f);
            s += g[i];
        }
        #pragma unroll
        for (int i = 0; i < 11; ++i) g[i] /= s;
    }

    float num = 0.0f, den = 0.0f;

    auto stage = [&](int gy0, int nrows) {
        for (int t = tid; t < nrows * NQ; t += 256) {
            int r = t / NQ, q = t - r * NQ;
            int gy = gy0 + r;
            int slot = (gy + 36) % RINGR;
            int gx = bx0 + 4 * q;
            float4 v1, v2, vm;
            if ((unsigned)gy < IMH && (unsigned)gx <= (IMW - 4)) {
                v1 = ld4s(p1 + gy * IMW + gx);
                v2 = ld4s(p2 + gy * IMW + gx);
                vm = ld4s(pm + gy * IMW + gx);
            } else if ((unsigned)gy < IMH) {
                float t1[4], t2[4], tm[4];
                #pragma unroll
                for (int e = 0; e < 4; ++e) {
                    int x = gx + e;
                    bool ok = (unsigned)x < IMW;
                    int off = gy * IMW + (ok ? x : 0);
                    t1[e] = ok ? p1[off] : 0.0f;
                    t2[e] = ok ? p2[off] : 0.0f;
                    tm[e] = ok ? pm[off] : 0.0f;
                }
                v1 = make_float4(t1[0], t1[1], t1[2], t1[3]);
                v2 = make_float4(t2[0], t2[1], t2[2], t2[3]);
                vm = make_float4(tm[0], tm[1], tm[2], tm[3]);
            } else {
                v1 = v2 = vm = make_float4(0.f, 0.f, 0.f, 0.f);
            }
            st4s(&ring1[slot][4 * q], v1);
            st4s(&ring2[slot][4 * q], v2);
            st4s(&ringm[slot][4 * q], vm);
        }
    };

    stage(ystart - 5, 10);

    for (int s = 0; s < FBNSUP; ++s) {
        const int ybase = ystart + s * SUP;
        stage(ybase + 5, SUP);
        __syncthreads();

        if (tid < SUP * NQ) {
            int r = tid / NQ, q = tid - r * NQ;
            int cq = 4 * q;
            int sr = (ybase + r + 31) % RINGR;
            float4 a1 = make_float4(0,0,0,0), a2 = a1, a3 = a1,
                   a4 = a1, a5 = a1, am = a1;
            #pragma unroll
            for (int k = 0; k < 11; ++k) {
                float4 x1 = ld4s(&ring1[sr][cq]);
                float4 x2 = ld4s(&ring2[sr][cq]);
                float4 xm = ld4s(&ringm[sr][cq]);
                float w = g[k];
                fma4(a1, w, x1);
                fma4(a2, w, x2);
                fma4m(a3, w, x1, x1);
                fma4m(a4, w, x2, x2);
                fma4m(a5, w, x1, x2);
                add4(am, xm);
                sr++; if (sr >= RINGR) sr -= RINGR;
            }
            st4s(&fld[0][r][cq], a1);
            st4s(&fld[1][r][cq], a2);
            st4s(&fld[2][r][cq], a3);
            st4s(&fld[3][r][cq], a4);
            st4s(&fld[4][r][cq], a5);
            st4s(&fld[5][r][cq], am);
        }
        __syncthreads();

        if (tid < SUP * 16) {
            int r = tid >> 4, q = tid & 15;
            int cb = 4 * q;
            float mu1[4], mu2[4], m11[4], m22[4], m12[4], mb[4];
            convg(fld[0][r], cb, g, mu1);
            convg(fld[1][r], cb, g, mu2);
            convg(fld[2][r], cb, g, m11);
            convg(fld[3][r], cb, g, m22);
            convg(fld[4][r], cb, g, m12);
            convb(fld[5][r], cb, mb);
            #pragma unroll
            for (int j = 0; j < 4; ++j) {
                float mu1s = mu1[j] * mu1[j];
                float mu2s = mu2[j] * mu2[j];
                float mu12 = mu1[j] * mu2[j];
                float sg1  = m11[j] - mu1s;
                float sg2  = m22[j] - mu2s;
                float sg12 = m12[j] - mu12;
                float ssim = ((2.0f * mu12 + 1e-4f) * (2.0f * sg12 + 9e-4f)) /
                             ((mu1s + mu2s + 1e-4f) * (sg1 + sg2 + 9e-4f));
                float m = mb[j] * (1.0f / 121.0f) + 1e-7f;
                float mask = (m > 0.5f) ? (1.0f + 1e-7f) : 1e-7f;
                num += (1.0f - ssim) * mask;
                den += mask;
            }
        }
    }

    for (int off = 32; off > 0; off >>= 1) {
        num += __shfl_down(num, off);
        den += __shfl_down(den, off);
    }
    int wave = tid >> 6;
    int lane = tid & 63;
    if (lane == 0) { redn[wave] = num; redd[wave] = den; }
    __syncthreads();
    if (tid == 0) {
        float n = redn[0] + redn[1] + redn[2] + redn[3];
        atomicAdd(&acc[0], (double)n);
        if (c == 0) {
            float d = redd[0] + redd[1] + redd[2] + redd[3];
            atomicAdd(&acc[1], (double)d);
        }
    }
}

__global__ void finalize(const double* __restrict__ acc, float* __restrict__ out) {
    out[0] = (float)(acc[0] / acc[1] / 3.0);
}

extern "C" void kernel_launch(void* const* d_in, const int* in_sizes, int n_in,
                              void* d_out, int out_size, void* d_ws, size_t ws_size,
                              hipStream_t stream) {
    const float* img1  = (const float*)d_in[0];
    const float* img2  = (const float*)d_in[1];
    const float* match = (const float*)d_in[2];
    float* out = (float*)d_out;
    double* acc = (double*)d_ws;                       // 16 B @ ws+0

    const size_t mask_need = 128 + (size_t)BATCH * IMH * IMW;  // 4,194,432 B
    const bool premask = (ws_size >= mask_need);
    float* gw = (float*)((char*)d_ws + 64);            // 44 B @ ws+64

    // zero acc[0..1] (doubles: all-zero bytes == +0.0); capturable async op
    hipMemsetAsync(d_ws, 0, 16, stream);

    dim3 block(256, 1, 1);
    if (premask) {
        unsigned char* mbuf = (unsigned char*)d_ws + 128;
        dim3 mgrid(IMW / MTW, IMH / MTH, BATCH);               // 8 x 8 x 16
        mask_pass<<<mgrid, block, 0, stream>>>(match, mbuf, gw, acc);
        dim3 grid(IMW / STRIPW, IMH / STRIPH, BATCH * CHANS);  // 8 x 8 x 48
        ssim_main_pm<<<grid, block, 0, stream>>>(img1, img2, mbuf, gw, acc);
    } else {
        dim3 grid(IMW / STRIPW, IMH / FBSTRIPH, BATCH * CHANS);
        ssim_main_fb<<<grid, block, 0, stream>>>(img1, img2, match, acc);
    }

    finalize<<<1, 1, 0, stream>>>(acc, out);
}